// Round 1
// baseline (375.505 us; speedup 1.0000x reference)
//
#include <hip/hip_runtime.h>

#define EPSV 1e-5f
constexpr int Bb = 4, Cc = 64, Nn = 40960, Kk = 16, Dd = 128;
constexpr int TPB = Nn / 16;               // 16-pt tiles per batch = 2560
constexpr int PPB = TPB / 2;               // 32-pt pairs per batch = 1280

typedef float f32x4 __attribute__((ext_vector_type(4)));
typedef __bf16 bf16x8 __attribute__((ext_vector_type(8)));
typedef unsigned short us8 __attribute__((ext_vector_type(8)));
typedef unsigned short us4 __attribute__((ext_vector_type(4)));

__device__ inline unsigned short f2bf(float x) {
    unsigned u = __builtin_bit_cast(unsigned, x);
    u += 0x7FFFu + ((u >> 16) & 1u);   // RNE
    return (unsigned short)(u >> 16);
}

// ---------------------------------------------------------------------------
// Prep: fold BN scale into bf16 weights, precompute shifts.
__global__ __launch_bounds__(256) void prep_weights(
    const float* __restrict__ w1, const float* __restrict__ g1, const float* __restrict__ b1,
    const float* __restrict__ m1, const float* __restrict__ v1,
    const float* __restrict__ w2, const float* __restrict__ g2, const float* __restrict__ b2,
    const float* __restrict__ m2, const float* __restrict__ v2,
    const float* __restrict__ w3, const float* __restrict__ g3, const float* __restrict__ b3,
    const float* __restrict__ m3, const float* __restrict__ v3,
    unsigned short* __restrict__ w1s, unsigned short* __restrict__ w2s, unsigned short* __restrict__ w3s,
    float* __restrict__ sh1, float* __restrict__ sh2, float* __restrict__ sh3) {
    const int e = blockIdx.x * 256 + threadIdx.x;
    if (e < 4096) {
        const int o = e >> 6;
        const float sc = g1[o] * rsqrtf(v1[o] + EPSV);
        w1s[e] = f2bf(w1[e] * sc);
    } else if (e < 12288) {
        const int i = e - 4096, o = i >> 6;
        const float sc = g2[o] * rsqrtf(v2[o] + EPSV);
        w2s[i] = f2bf(w2[i] * sc);
    } else if (e < 20480) {
        const int i = e - 12288, o = i >> 6;
        const float sc = g3[o] * rsqrtf(v3[o] + EPSV);
        w3s[i] = f2bf(w3[i] * sc);
    }
    if (e < 64) sh1[e] = b1[e] - m1[e] * (g1[e] * rsqrtf(v1[e] + EPSV));
    else if (e < 192) { const int d = e - 64;  sh2[d] = b2[d] - m2[d] * (g2[d] * rsqrtf(v2[d] + EPSV)); }
    else if (e < 320) { const int d = e - 192; sh3[d] = b3[d] - m3[d] * (g3[d] * rsqrtf(v3[d] + EPSV)); }
}

// ---------------------------------------------------------------------------
// Pass A: G1 = relu(sc1 * (W1 . f) + sh1), stored (B,N,64) bf16.
// ReLU+shift folded here (legal: relu is elementwise, shift is per-channel,
// so sum_k relu(G1[nb_k]+sh1) == sum_k of pre-relu'd rows).
__global__ __launch_bounds__(256) void passA(const float* __restrict__ f,
                                             const unsigned short* __restrict__ w1s,
                                             const float* __restrict__ sh1,
                                             unsigned short* __restrict__ G1) {
    __shared__ float s[64 * 65];                            // [ch][pt]
    __shared__ __attribute__((aligned(16))) unsigned short sg1[64 * 72];  // [pt][ch]

    const int tid = threadIdx.x, w = tid >> 6, lane = tid & 63;
    const int c15 = lane & 15, q = lane >> 4;
    const int b = blockIdx.x / 640;
    const int n0 = (blockIdx.x % 640) * 64;

    // load fp32 tile: [64 ch][64 pts]
    const float* src = f + ((size_t)b * Cc + w * 16) * Nn + n0 + lane;
#pragma unroll
    for (int i = 0; i < 16; ++i) s[(w * 16 + i) * 65 + lane] = src[(size_t)i * Nn];

    // weight B-frags: out-channel o1 = w*16 + c15
    const int o1 = w * 16 + c15;
    const float sh1v = sh1[o1];
    bf16x8 bw1[2];
#pragma unroll
    for (int ks = 0; ks < 2; ++ks)
        bw1[ks] = __builtin_bit_cast(bf16x8, *(const uint4*)(w1s + o1 * 64 + ks * 32 + q * 8));
    __syncthreads();

#pragma unroll
    for (int mt = 0; mt < 4; ++mt) {
        const int pt = mt * 16 + c15;
        us8 A0, A1;
#pragma unroll
        for (int j = 0; j < 8; ++j) A0[j] = f2bf(s[(q * 8 + j) * 65 + pt]);
#pragma unroll
        for (int j = 0; j < 8; ++j) A1[j] = f2bf(s[(32 + q * 8 + j) * 65 + pt]);
        f32x4 g = {0.f, 0.f, 0.f, 0.f};
        g = __builtin_amdgcn_mfma_f32_16x16x32_bf16(__builtin_bit_cast(bf16x8, A0), bw1[0], g, 0, 0, 0);
        g = __builtin_amdgcn_mfma_f32_16x16x32_bf16(__builtin_bit_cast(bf16x8, A1), bw1[1], g, 0, 0, 0);
#pragma unroll
        for (int r = 0; r < 4; ++r)
            sg1[(mt * 16 + q * 4 + r) * 72 + o1] = f2bf(fmaxf(g[r] + sh1v, 0.f));
    }
    __syncthreads();

    // coalesced store: thread (p = tid>>2, ck = tid&3) writes 32 B of row p
    {
        const int p = tid >> 2, ck = tid & 3;
        const uint4 v0 = *(const uint4*)(sg1 + p * 72 + ck * 16);
        const uint4 v1 = *(const uint4*)(sg1 + p * 72 + ck * 16 + 8);
        unsigned short* dst = G1 + ((size_t)b * Nn + n0 + p) * 64 + ck * 16;
        *(uint4*)dst = v0;
        *(uint4*)(dst + 8) = v1;
    }
}

// ---------------------------------------------------------------------------
// Pass B: one block = one 32-point pair (two 16-pt MFMA tiles).
// Both tiles' gathers interleaved in one loop (32 loads in flight, one
// latency exposure per 32 points); tile-B h1 parks in registers across
// tile-A MFMA; epilogue buffers 32 points so every nt-store instruction
// writes a full 128-B line (8 lanes x 16 B, row-contiguous).
__global__ __launch_bounds__(256, 6) void passB(
    const unsigned short* __restrict__ G1, const float* __restrict__ f,
    const int* __restrict__ idx,
    const unsigned short* __restrict__ w2s, const unsigned short* __restrict__ w3s,
    const float* __restrict__ sh2, const float* __restrict__ sh3,
    float* __restrict__ out) {
    __shared__ __attribute__((aligned(16))) unsigned short s_h1[16 * 72];   // 2304 B
    __shared__ float s_out[32 * 133];                                       // 17024 B

    const int tid  = threadIdx.x;
    const int wave = tid >> 6;
    const int lane = tid & 63;
    const int c15  = lane & 15;
    const int q    = lane >> 4;
    const int pg   = tid >> 4;              // gather-phase point 0..15 (per tile)
    const int cg   = tid & 15;              // gather-phase channel group (4 ch)

    const int pr = blockIdx.x;
    const int b  = pr / PPB;
    const int n0 = (pr - b * PPB) * 32;     // pair base point (128-B aligned in out)

    const unsigned short* G1b = G1 + (size_t)b * Nn * 64;
    const float* fb0 = f + (size_t)b * Cc * Nn;

    // neighbor indices for both tiles (issued first: gather depends on them)
    const int* idxp = idx + ((size_t)b * Nn + n0) * Kk;
    const int myidxA = idxp[tid];
    const int myidxB = idxp[256 + tid];

    // weight B-frags (register-resident, bf16 pre-scaled)
    float sh2v[2], sh3v[2];
    bf16x8 bw2[2][2], bw3[2][2];
#pragma unroll
    for (int nt = 0; nt < 2; ++nt) {
        const int d = wave * 32 + nt * 16 + c15;
        sh2v[nt] = sh2[d];
        sh3v[nt] = sh3[d];
#pragma unroll
        for (int ks = 0; ks < 2; ++ks) {
            bw2[nt][ks] = __builtin_bit_cast(bf16x8, *(const uint4*)(w2s + d * 64 + ks * 32 + q * 8));
            bw3[nt][ks] = __builtin_bit_cast(bf16x8, *(const uint4*)(w3s + d * 64 + ks * 32 + q * 8));
        }
    }

    // own-feature A-frags, tile A (strided fp32 -> bf16)
    us8 FA0, FA1;
    {
        const float* fown = fb0 + n0 + c15;
#pragma unroll
        for (int j = 0; j < 8; ++j) FA0[j] = f2bf(fown[(size_t)(q * 8 + j) * Nn]);
#pragma unroll
        for (int j = 0; j < 8; ++j) FA1[j] = f2bf(fown[(size_t)(32 + q * 8 + j) * Nn]);
    }

    // interleaved gather+sum for BOTH tiles (G1 rows already relu'd, so pure adds)
    float aA0 = 0.f, aA1 = 0.f, aA2 = 0.f, aA3 = 0.f;
    float aB0 = 0.f, aB1 = 0.f, aB2 = 0.f, aB3 = 0.f;
#pragma unroll
    for (int k = 0; k < 16; ++k) {
        const int la  = (pg & 3) * 16 + k;
        const int nbA = __shfl(myidxA, la, 64);
        const int nbB = __shfl(myidxB, la, 64);
        const uint2 dA = *(const uint2*)(G1b + (size_t)nbA * 64 + cg * 4);
        const uint2 dB = *(const uint2*)(G1b + (size_t)nbB * 64 + cg * 4);
        aA0 += __builtin_bit_cast(float, dA.x << 16);
        aA1 += __builtin_bit_cast(float, dA.x & 0xffff0000u);
        aA2 += __builtin_bit_cast(float, dA.y << 16);
        aA3 += __builtin_bit_cast(float, dA.y & 0xffff0000u);
        aB0 += __builtin_bit_cast(float, dB.x << 16);
        aB1 += __builtin_bit_cast(float, dB.x & 0xffff0000u);
        aB2 += __builtin_bit_cast(float, dB.y << 16);
        aB3 += __builtin_bit_cast(float, dB.y & 0xffff0000u);
    }

    // ---- tile A: h1 -> LDS ----
    {
        us4 hv;
        hv[0] = f2bf(aA0); hv[1] = f2bf(aA1); hv[2] = f2bf(aA2); hv[3] = f2bf(aA3);
        *(us4*)(s_h1 + pg * 72 + cg * 4) = hv;
    }
    __syncthreads();

    // ---- MFMA A -> s_out rows 0..15 ----
    {
        const unsigned short* h1row = s_h1 + c15 * 72;
        const bf16x8 ah0 = __builtin_bit_cast(bf16x8, *(const uint4*)(h1row + q * 8));
        const bf16x8 ah1 = __builtin_bit_cast(bf16x8, *(const uint4*)(h1row + 32 + q * 8));
        const bf16x8 af0 = __builtin_bit_cast(bf16x8, FA0);
        const bf16x8 af1 = __builtin_bit_cast(bf16x8, FA1);
#pragma unroll
        for (int nt = 0; nt < 2; ++nt) {
            f32x4 h2 = {sh2v[nt], sh2v[nt], sh2v[nt], sh2v[nt]};
            f32x4 s3 = {sh3v[nt], sh3v[nt], sh3v[nt], sh3v[nt]};
            h2 = __builtin_amdgcn_mfma_f32_16x16x32_bf16(ah0, bw2[nt][0], h2, 0, 0, 0);
            h2 = __builtin_amdgcn_mfma_f32_16x16x32_bf16(ah1, bw2[nt][1], h2, 0, 0, 0);
            s3 = __builtin_amdgcn_mfma_f32_16x16x32_bf16(af0, bw3[nt][0], s3, 0, 0, 0);
            s3 = __builtin_amdgcn_mfma_f32_16x16x32_bf16(af1, bw3[nt][1], s3, 0, 0, 0);
            const int d = wave * 32 + nt * 16 + c15;
#pragma unroll
            for (int r = 0; r < 4; ++r)
                s_out[(q * 4 + r) * 133 + d] = fmaxf(h2[r], 0.f) + fmaxf(s3[r], 0.f);
        }
    }
    __syncthreads();                        // s_h1(A) reads complete

    // ---- tile B: F-frags, h1 -> LDS ----
    us8 FB0, FB1;
    {
        const float* fown = fb0 + n0 + 16 + c15;
#pragma unroll
        for (int j = 0; j < 8; ++j) FB0[j] = f2bf(fown[(size_t)(q * 8 + j) * Nn]);
#pragma unroll
        for (int j = 0; j < 8; ++j) FB1[j] = f2bf(fown[(size_t)(32 + q * 8 + j) * Nn]);
    }
    {
        us4 hv;
        hv[0] = f2bf(aB0); hv[1] = f2bf(aB1); hv[2] = f2bf(aB2); hv[3] = f2bf(aB3);
        *(us4*)(s_h1 + pg * 72 + cg * 4) = hv;
    }
    __syncthreads();

    // ---- MFMA B -> s_out rows 16..31 ----
    {
        const unsigned short* h1row = s_h1 + c15 * 72;
        const bf16x8 ah0 = __builtin_bit_cast(bf16x8, *(const uint4*)(h1row + q * 8));
        const bf16x8 ah1 = __builtin_bit_cast(bf16x8, *(const uint4*)(h1row + 32 + q * 8));
        const bf16x8 af0 = __builtin_bit_cast(bf16x8, FB0);
        const bf16x8 af1 = __builtin_bit_cast(bf16x8, FB1);
#pragma unroll
        for (int nt = 0; nt < 2; ++nt) {
            f32x4 h2 = {sh2v[nt], sh2v[nt], sh2v[nt], sh2v[nt]};
            f32x4 s3 = {sh3v[nt], sh3v[nt], sh3v[nt], sh3v[nt]};
            h2 = __builtin_amdgcn_mfma_f32_16x16x32_bf16(ah0, bw2[nt][0], h2, 0, 0, 0);
            h2 = __builtin_amdgcn_mfma_f32_16x16x32_bf16(ah1, bw2[nt][1], h2, 0, 0, 0);
            s3 = __builtin_amdgcn_mfma_f32_16x16x32_bf16(af0, bw3[nt][0], s3, 0, 0, 0);
            s3 = __builtin_amdgcn_mfma_f32_16x16x32_bf16(af1, bw3[nt][1], s3, 0, 0, 0);
            const int d = wave * 32 + nt * 16 + c15;
#pragma unroll
            for (int r = 0; r < 4; ++r)
                s_out[(16 + q * 4 + r) * 133 + d] = fmaxf(h2[r], 0.f) + fmaxf(s3[r], 0.f);
        }
    }
    __syncthreads();

    // ---- full-line nontemporal store ----
    // 8 lanes x 16 B cover one 128-B line of row d (32 points); 4 passes x 32 rows.
    {
        const int dd = tid >> 3;            // 0..31: row within pass
        const int ck = tid & 7;             // 16-B chunk within line
#pragma unroll
        for (int r4 = 0; r4 < 4; ++r4) {
            const int d = r4 * 32 + dd;
            f32x4 v;
#pragma unroll
            for (int i = 0; i < 4; ++i) v[i] = s_out[(ck * 4 + i) * 133 + d];
            __builtin_nontemporal_store(v, (f32x4*)(out + ((size_t)b * Dd + d) * Nn + n0 + ck * 4));
        }
    }
}

extern "C" void kernel_launch(void* const* d_in, const int* in_sizes, int n_in,
                              void* d_out, int out_size, void* d_ws, size_t ws_size,
                              hipStream_t stream) {
    const float* feature = (const float*)d_in[0];
    const int*   neigh   = (const int*)d_in[1];
    const float* w1 = (const float*)d_in[2];
    const float* g1 = (const float*)d_in[3];
    const float* b1 = (const float*)d_in[4];
    const float* m1 = (const float*)d_in[5];
    const float* v1 = (const float*)d_in[6];
    const float* w2 = (const float*)d_in[7];
    const float* g2 = (const float*)d_in[8];
    const float* b2 = (const float*)d_in[9];
    const float* m2 = (const float*)d_in[10];
    const float* v2 = (const float*)d_in[11];
    const float* w3 = (const float*)d_in[12];
    const float* g3 = (const float*)d_in[13];
    const float* b3 = (const float*)d_in[14];
    const float* m3 = (const float*)d_in[15];
    const float* v3 = (const float*)d_in[16];
    float* out = (float*)d_out;

    char* ws = (char*)d_ws;
    unsigned short* G1  = (unsigned short*)ws;                        // 20,971,520 B
    unsigned short* w1s = (unsigned short*)(ws + 20971520);           //  8,192 B
    unsigned short* w2s = (unsigned short*)(ws + 20971520 + 8192);    // 16,384 B
    unsigned short* w3s = (unsigned short*)(ws + 20971520 + 24576);   // 16,384 B
    float* sh1 = (float*)(ws + 20971520 + 40960);
    float* sh2 = (float*)(ws + 20971520 + 41216);
    float* sh3 = (float*)(ws + 20971520 + 41728);

    prep_weights<<<80, 256, 0, stream>>>(w1, g1, b1, m1, v1, w2, g2, b2, m2, v2,
                                         w3, g3, b3, m3, v3, w1s, w2s, w3s, sh1, sh2, sh3);
    passA<<<Bb * 640, 256, 0, stream>>>(feature, w1s, sh1, G1);
    passB<<<Bb * PPB, 256, 0, stream>>>(G1, feature, neigh, w2s, w3s,
                                        sh2, sh3, out);
}

// Round 2
// 288.412 us; speedup vs baseline: 1.3020x; 1.3020x over previous
//
#include <hip/hip_runtime.h>

#define EPSV 1e-5f
constexpr int Bb = 4, Cc = 64, Nn = 40960, Kk = 16, Dd = 128;
constexpr int TPB = Nn / 16;               // 16-pt tiles per batch = 2560
constexpr int PPB = TPB / 2;               // 32-pt pairs per batch = 1280

typedef float f32x4 __attribute__((ext_vector_type(4)));
typedef __bf16 bf16x8 __attribute__((ext_vector_type(8)));
typedef unsigned short us8 __attribute__((ext_vector_type(8)));
typedef unsigned short us4 __attribute__((ext_vector_type(4)));

__device__ inline unsigned short f2bf(float x) {
    unsigned u = __builtin_bit_cast(unsigned, x);
    u += 0x7FFFu + ((u >> 16) & 1u);   // RNE
    return (unsigned short)(u >> 16);
}

// ---------------------------------------------------------------------------
// Prep: fold BN scale into bf16 weights, precompute shifts.
__global__ __launch_bounds__(256) void prep_weights(
    const float* __restrict__ w1, const float* __restrict__ g1, const float* __restrict__ b1,
    const float* __restrict__ m1, const float* __restrict__ v1,
    const float* __restrict__ w2, const float* __restrict__ g2, const float* __restrict__ b2,
    const float* __restrict__ m2, const float* __restrict__ v2,
    const float* __restrict__ w3, const float* __restrict__ g3, const float* __restrict__ b3,
    const float* __restrict__ m3, const float* __restrict__ v3,
    unsigned short* __restrict__ w1s, unsigned short* __restrict__ w2s, unsigned short* __restrict__ w3s,
    float* __restrict__ sh1, float* __restrict__ sh2, float* __restrict__ sh3) {
    const int e = blockIdx.x * 256 + threadIdx.x;
    if (e < 4096) {
        const int o = e >> 6;
        const float sc = g1[o] * rsqrtf(v1[o] + EPSV);
        w1s[e] = f2bf(w1[e] * sc);
    } else if (e < 12288) {
        const int i = e - 4096, o = i >> 6;
        const float sc = g2[o] * rsqrtf(v2[o] + EPSV);
        w2s[i] = f2bf(w2[i] * sc);
    } else if (e < 20480) {
        const int i = e - 12288, o = i >> 6;
        const float sc = g3[o] * rsqrtf(v3[o] + EPSV);
        w3s[i] = f2bf(w3[i] * sc);
    }
    if (e < 64) sh1[e] = b1[e] - m1[e] * (g1[e] * rsqrtf(v1[e] + EPSV));
    else if (e < 192) { const int d = e - 64;  sh2[d] = b2[d] - m2[d] * (g2[d] * rsqrtf(v2[d] + EPSV)); }
    else if (e < 320) { const int d = e - 192; sh3[d] = b3[d] - m3[d] * (g3[d] * rsqrtf(v3[d] + EPSV)); }
}

// ---------------------------------------------------------------------------
// Pass A: G1 = relu(sc1 * (W1 . f) + sh1), stored (B,N,64) bf16.
// ReLU+shift folded here (legal: relu is elementwise, shift is per-channel,
// so sum_k relu(G1[nb_k]+sh1) == sum_k of pre-relu'd rows).
__global__ __launch_bounds__(256) void passA(const float* __restrict__ f,
                                             const unsigned short* __restrict__ w1s,
                                             const float* __restrict__ sh1,
                                             unsigned short* __restrict__ G1) {
    __shared__ float s[64 * 65];                            // [ch][pt]
    __shared__ __attribute__((aligned(16))) unsigned short sg1[64 * 72];  // [pt][ch]

    const int tid = threadIdx.x, w = tid >> 6, lane = tid & 63;
    const int c15 = lane & 15, q = lane >> 4;
    const int b = blockIdx.x / 640;
    const int n0 = (blockIdx.x % 640) * 64;

    // load fp32 tile: [64 ch][64 pts]
    const float* src = f + ((size_t)b * Cc + w * 16) * Nn + n0 + lane;
#pragma unroll
    for (int i = 0; i < 16; ++i) s[(w * 16 + i) * 65 + lane] = src[(size_t)i * Nn];

    // weight B-frags: out-channel o1 = w*16 + c15
    const int o1 = w * 16 + c15;
    const float sh1v = sh1[o1];
    bf16x8 bw1[2];
#pragma unroll
    for (int ks = 0; ks < 2; ++ks)
        bw1[ks] = __builtin_bit_cast(bf16x8, *(const uint4*)(w1s + o1 * 64 + ks * 32 + q * 8));
    __syncthreads();

#pragma unroll
    for (int mt = 0; mt < 4; ++mt) {
        const int pt = mt * 16 + c15;
        us8 A0, A1;
#pragma unroll
        for (int j = 0; j < 8; ++j) A0[j] = f2bf(s[(q * 8 + j) * 65 + pt]);
#pragma unroll
        for (int j = 0; j < 8; ++j) A1[j] = f2bf(s[(32 + q * 8 + j) * 65 + pt]);
        f32x4 g = {0.f, 0.f, 0.f, 0.f};
        g = __builtin_amdgcn_mfma_f32_16x16x32_bf16(__builtin_bit_cast(bf16x8, A0), bw1[0], g, 0, 0, 0);
        g = __builtin_amdgcn_mfma_f32_16x16x32_bf16(__builtin_bit_cast(bf16x8, A1), bw1[1], g, 0, 0, 0);
#pragma unroll
        for (int r = 0; r < 4; ++r)
            sg1[(mt * 16 + q * 4 + r) * 72 + o1] = f2bf(fmaxf(g[r] + sh1v, 0.f));
    }
    __syncthreads();

    // coalesced store: thread (p = tid>>2, ck = tid&3) writes 32 B of row p
    {
        const int p = tid >> 2, ck = tid & 3;
        const uint4 v0 = *(const uint4*)(sg1 + p * 72 + ck * 16);
        const uint4 v1 = *(const uint4*)(sg1 + p * 72 + ck * 16 + 8);
        unsigned short* dst = G1 + ((size_t)b * Nn + n0 + p) * 64 + ck * 16;
        *(uint4*)dst = v0;
        *(uint4*)(dst + 8) = v1;
    }
}

// ---------------------------------------------------------------------------
// Pass B: one block = one 32-point pair (two 16-pt MFMA tiles).
// Both tiles' gathers interleaved in one loop (32 loads in flight, one
// latency exposure per 32 points); tile-B h1 parks in registers across
// tile-A MFMA; epilogue buffers 32 points so every nt-store instruction
// group writes a full 128-B line (8 lanes x 16 B, row-contiguous).
// launch_bounds (256,4): VGPR cap 128 — (256,6) capped at ~85 and spilled
// the weight/feature frags to scratch (+760 MB deterministic HBM traffic).
__global__ __launch_bounds__(256, 4) void passB(
    const unsigned short* __restrict__ G1, const float* __restrict__ f,
    const int* __restrict__ idx,
    const unsigned short* __restrict__ w2s, const unsigned short* __restrict__ w3s,
    const float* __restrict__ sh2, const float* __restrict__ sh3,
    float* __restrict__ out) {
    __shared__ __attribute__((aligned(16))) unsigned short s_h1[16 * 72];   // 2304 B
    __shared__ float s_out[32 * 133];                                       // 17024 B

    const int tid  = threadIdx.x;
    const int wave = tid >> 6;
    const int lane = tid & 63;
    const int c15  = lane & 15;
    const int q    = lane >> 4;
    const int pg   = tid >> 4;              // gather-phase point 0..15 (per tile)
    const int cg   = tid & 15;              // gather-phase channel group (4 ch)

    const int pr = blockIdx.x;
    const int b  = pr / PPB;
    const int n0 = (pr - b * PPB) * 32;     // pair base point (128-B aligned in out)

    const unsigned short* G1b = G1 + (size_t)b * Nn * 64;
    const float* fb0 = f + (size_t)b * Cc * Nn;

    // neighbor indices for both tiles (issued first: gather depends on them)
    const int* idxp = idx + ((size_t)b * Nn + n0) * Kk;
    const int myidxA = idxp[tid];
    const int myidxB = idxp[256 + tid];

    // weight B-frags (register-resident, bf16 pre-scaled)
    float sh2v[2], sh3v[2];
    bf16x8 bw2[2][2], bw3[2][2];
#pragma unroll
    for (int nt = 0; nt < 2; ++nt) {
        const int d = wave * 32 + nt * 16 + c15;
        sh2v[nt] = sh2[d];
        sh3v[nt] = sh3[d];
#pragma unroll
        for (int ks = 0; ks < 2; ++ks) {
            bw2[nt][ks] = __builtin_bit_cast(bf16x8, *(const uint4*)(w2s + d * 64 + ks * 32 + q * 8));
            bw3[nt][ks] = __builtin_bit_cast(bf16x8, *(const uint4*)(w3s + d * 64 + ks * 32 + q * 8));
        }
    }

    // own-feature A-frags, tile A (strided fp32 -> bf16)
    us8 FA0, FA1;
    {
        const float* fown = fb0 + n0 + c15;
#pragma unroll
        for (int j = 0; j < 8; ++j) FA0[j] = f2bf(fown[(size_t)(q * 8 + j) * Nn]);
#pragma unroll
        for (int j = 0; j < 8; ++j) FA1[j] = f2bf(fown[(size_t)(32 + q * 8 + j) * Nn]);
    }

    // interleaved gather+sum for BOTH tiles (G1 rows already relu'd, so pure adds)
    float aA0 = 0.f, aA1 = 0.f, aA2 = 0.f, aA3 = 0.f;
    float aB0 = 0.f, aB1 = 0.f, aB2 = 0.f, aB3 = 0.f;
#pragma unroll
    for (int k = 0; k < 16; ++k) {
        const int la  = (pg & 3) * 16 + k;
        const int nbA = __shfl(myidxA, la, 64);
        const int nbB = __shfl(myidxB, la, 64);
        const uint2 dA = *(const uint2*)(G1b + (size_t)nbA * 64 + cg * 4);
        const uint2 dB = *(const uint2*)(G1b + (size_t)nbB * 64 + cg * 4);
        aA0 += __builtin_bit_cast(float, dA.x << 16);
        aA1 += __builtin_bit_cast(float, dA.x & 0xffff0000u);
        aA2 += __builtin_bit_cast(float, dA.y << 16);
        aA3 += __builtin_bit_cast(float, dA.y & 0xffff0000u);
        aB0 += __builtin_bit_cast(float, dB.x << 16);
        aB1 += __builtin_bit_cast(float, dB.x & 0xffff0000u);
        aB2 += __builtin_bit_cast(float, dB.y << 16);
        aB3 += __builtin_bit_cast(float, dB.y & 0xffff0000u);
    }

    // ---- tile A: h1 -> LDS ----
    {
        us4 hv;
        hv[0] = f2bf(aA0); hv[1] = f2bf(aA1); hv[2] = f2bf(aA2); hv[3] = f2bf(aA3);
        *(us4*)(s_h1 + pg * 72 + cg * 4) = hv;
    }
    __syncthreads();

    // ---- MFMA A -> s_out rows 0..15 ----
    {
        const unsigned short* h1row = s_h1 + c15 * 72;
        const bf16x8 ah0 = __builtin_bit_cast(bf16x8, *(const uint4*)(h1row + q * 8));
        const bf16x8 ah1 = __builtin_bit_cast(bf16x8, *(const uint4*)(h1row + 32 + q * 8));
        const bf16x8 af0 = __builtin_bit_cast(bf16x8, FA0);
        const bf16x8 af1 = __builtin_bit_cast(bf16x8, FA1);
#pragma unroll
        for (int nt = 0; nt < 2; ++nt) {
            f32x4 h2 = {sh2v[nt], sh2v[nt], sh2v[nt], sh2v[nt]};
            f32x4 s3 = {sh3v[nt], sh3v[nt], sh3v[nt], sh3v[nt]};
            h2 = __builtin_amdgcn_mfma_f32_16x16x32_bf16(ah0, bw2[nt][0], h2, 0, 0, 0);
            h2 = __builtin_amdgcn_mfma_f32_16x16x32_bf16(ah1, bw2[nt][1], h2, 0, 0, 0);
            s3 = __builtin_amdgcn_mfma_f32_16x16x32_bf16(af0, bw3[nt][0], s3, 0, 0, 0);
            s3 = __builtin_amdgcn_mfma_f32_16x16x32_bf16(af1, bw3[nt][1], s3, 0, 0, 0);
            const int d = wave * 32 + nt * 16 + c15;
#pragma unroll
            for (int r = 0; r < 4; ++r)
                s_out[(q * 4 + r) * 133 + d] = fmaxf(h2[r], 0.f) + fmaxf(s3[r], 0.f);
        }
    }
    __syncthreads();                        // s_h1(A) reads complete

    // ---- tile B: F-frags, h1 -> LDS ----
    us8 FB0, FB1;
    {
        const float* fown = fb0 + n0 + 16 + c15;
#pragma unroll
        for (int j = 0; j < 8; ++j) FB0[j] = f2bf(fown[(size_t)(q * 8 + j) * Nn]);
#pragma unroll
        for (int j = 0; j < 8; ++j) FB1[j] = f2bf(fown[(size_t)(32 + q * 8 + j) * Nn]);
    }
    {
        us4 hv;
        hv[0] = f2bf(aB0); hv[1] = f2bf(aB1); hv[2] = f2bf(aB2); hv[3] = f2bf(aB3);
        *(us4*)(s_h1 + pg * 72 + cg * 4) = hv;
    }
    __syncthreads();

    // ---- MFMA B -> s_out rows 16..31 ----
    {
        const unsigned short* h1row = s_h1 + c15 * 72;
        const bf16x8 ah0 = __builtin_bit_cast(bf16x8, *(const uint4*)(h1row + q * 8));
        const bf16x8 ah1 = __builtin_bit_cast(bf16x8, *(const uint4*)(h1row + 32 + q * 8));
        const bf16x8 af0 = __builtin_bit_cast(bf16x8, FB0);
        const bf16x8 af1 = __builtin_bit_cast(bf16x8, FB1);
#pragma unroll
        for (int nt = 0; nt < 2; ++nt) {
            f32x4 h2 = {sh2v[nt], sh2v[nt], sh2v[nt], sh2v[nt]};
            f32x4 s3 = {sh3v[nt], sh3v[nt], sh3v[nt], sh3v[nt]};
            h2 = __builtin_amdgcn_mfma_f32_16x16x32_bf16(ah0, bw2[nt][0], h2, 0, 0, 0);
            h2 = __builtin_amdgcn_mfma_f32_16x16x32_bf16(ah1, bw2[nt][1], h2, 0, 0, 0);
            s3 = __builtin_amdgcn_mfma_f32_16x16x32_bf16(af0, bw3[nt][0], s3, 0, 0, 0);
            s3 = __builtin_amdgcn_mfma_f32_16x16x32_bf16(af1, bw3[nt][1], s3, 0, 0, 0);
            const int d = wave * 32 + nt * 16 + c15;
#pragma unroll
            for (int r = 0; r < 4; ++r)
                s_out[(16 + q * 4 + r) * 133 + d] = fmaxf(h2[r], 0.f) + fmaxf(s3[r], 0.f);
        }
    }
    __syncthreads();

    // ---- full-line nontemporal store ----
    // 8 lanes x 16 B cover one 128-B line of row d (32 points); 4 passes x 32 rows.
    {
        const int dd = tid >> 3;            // 0..31: row within pass
        const int ck = tid & 7;             // 16-B chunk within line
#pragma unroll
        for (int r4 = 0; r4 < 4; ++r4) {
            const int d = r4 * 32 + dd;
            f32x4 v;
#pragma unroll
            for (int i = 0; i < 4; ++i) v[i] = s_out[(ck * 4 + i) * 133 + d];
            __builtin_nontemporal_store(v, (f32x4*)(out + ((size_t)b * Dd + d) * Nn + n0 + ck * 4));
        }
    }
}

extern "C" void kernel_launch(void* const* d_in, const int* in_sizes, int n_in,
                              void* d_out, int out_size, void* d_ws, size_t ws_size,
                              hipStream_t stream) {
    const float* feature = (const float*)d_in[0];
    const int*   neigh   = (const int*)d_in[1];
    const float* w1 = (const float*)d_in[2];
    const float* g1 = (const float*)d_in[3];
    const float* b1 = (const float*)d_in[4];
    const float* m1 = (const float*)d_in[5];
    const float* v1 = (const float*)d_in[6];
    const float* w2 = (const float*)d_in[7];
    const float* g2 = (const float*)d_in[8];
    const float* b2 = (const float*)d_in[9];
    const float* m2 = (const float*)d_in[10];
    const float* v2 = (const float*)d_in[11];
    const float* w3 = (const float*)d_in[12];
    const float* g3 = (const float*)d_in[13];
    const float* b3 = (const float*)d_in[14];
    const float* m3 = (const float*)d_in[15];
    const float* v3 = (const float*)d_in[16];
    float* out = (float*)d_out;

    char* ws = (char*)d_ws;
    unsigned short* G1  = (unsigned short*)ws;                        // 20,971,520 B
    unsigned short* w1s = (unsigned short*)(ws + 20971520);           //  8,192 B
    unsigned short* w2s = (unsigned short*)(ws + 20971520 + 8192);    // 16,384 B
    unsigned short* w3s = (unsigned short*)(ws + 20971520 + 24576);   // 16,384 B
    float* sh1 = (float*)(ws + 20971520 + 40960);
    float* sh2 = (float*)(ws + 20971520 + 41216);
    float* sh3 = (float*)(ws + 20971520 + 41728);

    prep_weights<<<80, 256, 0, stream>>>(w1, g1, b1, m1, v1, w2, g2, b2, m2, v2,
                                         w3, g3, b3, m3, v3, w1s, w2s, w3s, sh1, sh2, sh3);
    passA<<<Bb * 640, 256, 0, stream>>>(feature, w1s, sh1, G1);
    passB<<<Bb * PPB, 256, 0, stream>>>(G1, feature, neigh, w2s, w3s,
                                        sh2, sh3, out);
}

// Round 3
// 214.402 us; speedup vs baseline: 1.7514x; 1.3452x over previous
//
#include <hip/hip_runtime.h>

#define EPSV 1e-5f
constexpr int Bb = 4, Cc = 64, Nn = 40960, Kk = 16, Dd = 128;
constexpr int G = 4;                       // point-tiles per block in pass B (even!)
constexpr int TPB = Nn / 16;               // tiles per batch = 2560

typedef float f32x4 __attribute__((ext_vector_type(4)));
typedef __bf16 bf16x8 __attribute__((ext_vector_type(8)));
typedef unsigned short us8 __attribute__((ext_vector_type(8)));
typedef unsigned short us4 __attribute__((ext_vector_type(4)));

__device__ inline unsigned short f2bf(float x) {
    unsigned u = __builtin_bit_cast(unsigned, x);
    u += 0x7FFFu + ((u >> 16) & 1u);   // RNE
    return (unsigned short)(u >> 16);
}

// ---------------------------------------------------------------------------
// Prep: fold BN scale into bf16 weights, precompute shifts.
__global__ __launch_bounds__(256) void prep_weights(
    const float* __restrict__ w1, const float* __restrict__ g1, const float* __restrict__ b1,
    const float* __restrict__ m1, const float* __restrict__ v1,
    const float* __restrict__ w2, const float* __restrict__ g2, const float* __restrict__ b2,
    const float* __restrict__ m2, const float* __restrict__ v2,
    const float* __restrict__ w3, const float* __restrict__ g3, const float* __restrict__ b3,
    const float* __restrict__ m3, const float* __restrict__ v3,
    unsigned short* __restrict__ w1s, unsigned short* __restrict__ w2s, unsigned short* __restrict__ w3s,
    float* __restrict__ sh1, float* __restrict__ sh2, float* __restrict__ sh3) {
    const int e = blockIdx.x * 256 + threadIdx.x;
    if (e < 4096) {
        const int o = e >> 6;
        const float sc = g1[o] * rsqrtf(v1[o] + EPSV);
        w1s[e] = f2bf(w1[e] * sc);
    } else if (e < 12288) {
        const int i = e - 4096, o = i >> 6;
        const float sc = g2[o] * rsqrtf(v2[o] + EPSV);
        w2s[i] = f2bf(w2[i] * sc);
    } else if (e < 20480) {
        const int i = e - 12288, o = i >> 6;
        const float sc = g3[o] * rsqrtf(v3[o] + EPSV);
        w3s[i] = f2bf(w3[i] * sc);
    }
    if (e < 64) sh1[e] = b1[e] - m1[e] * (g1[e] * rsqrtf(v1[e] + EPSV));
    else if (e < 192) { const int d = e - 64;  sh2[d] = b2[d] - m2[d] * (g2[d] * rsqrtf(v2[d] + EPSV)); }
    else if (e < 320) { const int d = e - 192; sh3[d] = b3[d] - m3[d] * (g3[d] * rsqrtf(v3[d] + EPSV)); }
}

// ---------------------------------------------------------------------------
// Pass A: G1 = relu(sc1 * (W1 . f) + sh1), stored (B,N,64) bf16.
// ReLU+shift folded here (legal: relu elementwise, shift per-channel, so
// sum_k relu(G1[nb_k]+sh1) == sum_k of pre-relu'd rows). Validated rounds 1-2.
__global__ __launch_bounds__(256) void passA(const float* __restrict__ f,
                                             const unsigned short* __restrict__ w1s,
                                             const float* __restrict__ sh1,
                                             unsigned short* __restrict__ G1) {
    __shared__ float s[64 * 65];                            // [ch][pt]
    __shared__ __attribute__((aligned(16))) unsigned short sg1[64 * 72];  // [pt][ch]

    const int tid = threadIdx.x, w = tid >> 6, lane = tid & 63;
    const int c15 = lane & 15, q = lane >> 4;
    const int b = blockIdx.x / 640;
    const int n0 = (blockIdx.x % 640) * 64;

    // load fp32 tile: [64 ch][64 pts]
    const float* src = f + ((size_t)b * Cc + w * 16) * Nn + n0 + lane;
#pragma unroll
    for (int i = 0; i < 16; ++i) s[(w * 16 + i) * 65 + lane] = src[(size_t)i * Nn];

    // weight B-frags: out-channel o1 = w*16 + c15
    const int o1 = w * 16 + c15;
    const float sh1v = sh1[o1];
    bf16x8 bw1[2];
#pragma unroll
    for (int ks = 0; ks < 2; ++ks)
        bw1[ks] = __builtin_bit_cast(bf16x8, *(const uint4*)(w1s + o1 * 64 + ks * 32 + q * 8));
    __syncthreads();

#pragma unroll
    for (int mt = 0; mt < 4; ++mt) {
        const int pt = mt * 16 + c15;
        us8 A0, A1;
#pragma unroll
        for (int j = 0; j < 8; ++j) A0[j] = f2bf(s[(q * 8 + j) * 65 + pt]);
#pragma unroll
        for (int j = 0; j < 8; ++j) A1[j] = f2bf(s[(32 + q * 8 + j) * 65 + pt]);
        f32x4 g = {0.f, 0.f, 0.f, 0.f};
        g = __builtin_amdgcn_mfma_f32_16x16x32_bf16(__builtin_bit_cast(bf16x8, A0), bw1[0], g, 0, 0, 0);
        g = __builtin_amdgcn_mfma_f32_16x16x32_bf16(__builtin_bit_cast(bf16x8, A1), bw1[1], g, 0, 0, 0);
#pragma unroll
        for (int r = 0; r < 4; ++r)
            sg1[(mt * 16 + q * 4 + r) * 72 + o1] = f2bf(fmaxf(g[r] + sh1v, 0.f));
    }
    __syncthreads();

    // coalesced store: thread (p = tid>>2, ck = tid&3) writes 32 B of row p
    {
        const int p = tid >> 2, ck = tid & 3;
        const uint4 v0 = *(const uint4*)(sg1 + p * 72 + ck * 16);
        const uint4 v1 = *(const uint4*)(sg1 + p * 72 + ck * 16 + 8);
        unsigned short* dst = G1 + ((size_t)b * Nn + n0 + p) * 64 + ck * 16;
        *(uint4*)dst = v0;
        *(uint4*)(dst + 8) = v1;
    }
}

// ---------------------------------------------------------------------------
// Pass B: round-0 per-16-pt-tile skeleton (one tile's state live at a time —
// 64 VGPR, no spill; the round-1/2 pair-tile variant spilled to scratch).
// New vs round 0: (a) gather is pure adds (relu folded into passA),
// (b) s_out buffers TWO tiles so the nt-store epilogue (every other g)
// writes full 128-B lines, (c) idx row for g+1 prefetched into a register.
__global__ __launch_bounds__(256, 4) void passB(
    const unsigned short* __restrict__ G1, const float* __restrict__ f,
    const int* __restrict__ idx,
    const unsigned short* __restrict__ w2s, const unsigned short* __restrict__ w3s,
    const float* __restrict__ sh2, const float* __restrict__ sh3,
    float* __restrict__ out) {
    __shared__ __attribute__((aligned(16))) unsigned short s_h1[16 * 72];   // 2304 B
    __shared__ float s_out[32 * 133];                                       // 17024 B

    const int tid  = threadIdx.x;
    const int wave = tid >> 6;
    const int lane = tid & 63;
    const int c15  = lane & 15;
    const int q    = lane >> 4;
    const int pg   = tid >> 4;              // gather-phase point 0..15
    const int cg   = tid & 15;              // gather-phase channel group (4 ch)

    const int t0  = blockIdx.x * G;
    const int b   = t0 / TPB;               // 640 blocks per batch, G|TPB
    const int nb0 = (t0 - b * TPB) * 16;    // multiple of 64 -> pair bases line-aligned

    // weight B-frags (register-resident, bf16 pre-scaled)
    float sh2v[2], sh3v[2];
    bf16x8 bw2[2][2], bw3[2][2];
#pragma unroll
    for (int nt = 0; nt < 2; ++nt) {
        const int d = wave * 32 + nt * 16 + c15;
        sh2v[nt] = sh2[d];
        sh3v[nt] = sh3[d];
#pragma unroll
        for (int ks = 0; ks < 2; ++ks) {
            bw2[nt][ks] = __builtin_bit_cast(bf16x8, *(const uint4*)(w2s + d * 64 + ks * 32 + q * 8));
            bw3[nt][ks] = __builtin_bit_cast(bf16x8, *(const uint4*)(w3s + d * 64 + ks * 32 + q * 8));
        }
    }

    const unsigned short* G1b = G1 + (size_t)b * Nn * 64;
    const float* fb0 = f + (size_t)b * Cc * Nn;
    const int* idxp = idx + ((size_t)b * Nn + nb0) * Kk;

    int myidx = idxp[tid];                  // tile 0's idx row

    for (int g = 0; g < G; ++g) {
        const int n0 = nb0 + g * 16;

        // prefetch next tile's idx row (hides idx-load latency under this tile)
        const int myidxN = (g + 1 < G) ? idxp[(g + 1) * 256 + tid] : 0;

        // own-feature A-frags for the W3 skip path (strided fp32 -> bf16)
        const float* fown = fb0 + n0 + c15;
        us8 F0, F1;
#pragma unroll
        for (int j = 0; j < 8; ++j) F0[j] = f2bf(fown[(size_t)(q * 8 + j) * Nn]);
#pragma unroll
        for (int j = 0; j < 8; ++j) F1[j] = f2bf(fown[(size_t)(32 + q * 8 + j) * Nn]);

        // gather + sum: thread (pg, cg) accumulates 4 channels over 16 nbrs.
        // G1 rows are already relu'd (passA), so this is pure adds.
        float a0 = 0.f, a1 = 0.f, a2 = 0.f, a3 = 0.f;
#pragma unroll
        for (int k = 0; k < 16; ++k) {
            const int nb = __shfl(myidx, (pg & 3) * 16 + k, 64);
            const uint2 d2 = *(const uint2*)(G1b + (size_t)nb * 64 + cg * 4);
            a0 += __builtin_bit_cast(float, d2.x << 16);
            a1 += __builtin_bit_cast(float, d2.x & 0xffff0000u);
            a2 += __builtin_bit_cast(float, d2.y << 16);
            a3 += __builtin_bit_cast(float, d2.y & 0xffff0000u);
        }
        myidx = myidxN;

        __syncthreads();                     // prev iter's s_h1/s_out reads done
        us4 hv;
        hv[0] = f2bf(a0); hv[1] = f2bf(a1); hv[2] = f2bf(a2); hv[3] = f2bf(a3);
        *(us4*)(s_h1 + pg * 72 + cg * 4) = hv;
        __syncthreads();

        // GEMM2 (W2 . h1) + skip (W3 . f_own)
        const unsigned short* h1row = s_h1 + c15 * 72;
        const bf16x8 ah0 = __builtin_bit_cast(bf16x8, *(const uint4*)(h1row + q * 8));
        const bf16x8 ah1 = __builtin_bit_cast(bf16x8, *(const uint4*)(h1row + 32 + q * 8));
        const bf16x8 af0 = __builtin_bit_cast(bf16x8, F0);
        const bf16x8 af1 = __builtin_bit_cast(bf16x8, F1);

        const int prow = (g & 1) * 16;       // s_out row base for this tile
#pragma unroll
        for (int nt = 0; nt < 2; ++nt) {
            f32x4 h2 = {sh2v[nt], sh2v[nt], sh2v[nt], sh2v[nt]};
            f32x4 s3 = {sh3v[nt], sh3v[nt], sh3v[nt], sh3v[nt]};
            h2 = __builtin_amdgcn_mfma_f32_16x16x32_bf16(ah0, bw2[nt][0], h2, 0, 0, 0);
            h2 = __builtin_amdgcn_mfma_f32_16x16x32_bf16(ah1, bw2[nt][1], h2, 0, 0, 0);
            s3 = __builtin_amdgcn_mfma_f32_16x16x32_bf16(af0, bw3[nt][0], s3, 0, 0, 0);
            s3 = __builtin_amdgcn_mfma_f32_16x16x32_bf16(af1, bw3[nt][1], s3, 0, 0, 0);
            const int d = wave * 32 + nt * 16 + c15;
#pragma unroll
            for (int r = 0; r < 4; ++r)
                s_out[(prow + q * 4 + r) * 133 + d] = fmaxf(h2[r], 0.f) + fmaxf(s3[r], 0.f);
        }
        __syncthreads();

        // full-line nontemporal store every 2 tiles:
        // 8 lanes x 16 B cover one 128-B line of row d (32 points); 4 passes.
        if (g & 1) {
            const int np = n0 - 16;          // pair base point (line-aligned)
            const int dd = tid >> 3;         // 0..31: row within pass
            const int ck = tid & 7;          // 16-B chunk within line
#pragma unroll
            for (int r4 = 0; r4 < 4; ++r4) {
                const int d = r4 * 32 + dd;
                f32x4 v;
#pragma unroll
                for (int i = 0; i < 4; ++i) v[i] = s_out[(ck * 4 + i) * 133 + d];
                __builtin_nontemporal_store(v, (f32x4*)(out + ((size_t)b * Dd + d) * Nn + np + ck * 4));
            }
        }
    }
}

extern "C" void kernel_launch(void* const* d_in, const int* in_sizes, int n_in,
                              void* d_out, int out_size, void* d_ws, size_t ws_size,
                              hipStream_t stream) {
    const float* feature = (const float*)d_in[0];
    const int*   neigh   = (const int*)d_in[1];
    const float* w1 = (const float*)d_in[2];
    const float* g1 = (const float*)d_in[3];
    const float* b1 = (const float*)d_in[4];
    const float* m1 = (const float*)d_in[5];
    const float* v1 = (const float*)d_in[6];
    const float* w2 = (const float*)d_in[7];
    const float* g2 = (const float*)d_in[8];
    const float* b2 = (const float*)d_in[9];
    const float* m2 = (const float*)d_in[10];
    const float* v2 = (const float*)d_in[11];
    const float* w3 = (const float*)d_in[12];
    const float* g3 = (const float*)d_in[13];
    const float* b3 = (const float*)d_in[14];
    const float* m3 = (const float*)d_in[15];
    const float* v3 = (const float*)d_in[16];
    float* out = (float*)d_out;

    char* ws = (char*)d_ws;
    unsigned short* G1  = (unsigned short*)ws;                        // 20,971,520 B
    unsigned short* w1s = (unsigned short*)(ws + 20971520);           //  8,192 B
    unsigned short* w2s = (unsigned short*)(ws + 20971520 + 8192);    // 16,384 B
    unsigned short* w3s = (unsigned short*)(ws + 20971520 + 24576);   // 16,384 B
    float* sh1 = (float*)(ws + 20971520 + 40960);
    float* sh2 = (float*)(ws + 20971520 + 41216);
    float* sh3 = (float*)(ws + 20971520 + 41728);

    prep_weights<<<80, 256, 0, stream>>>(w1, g1, b1, m1, v1, w2, g2, b2, m2, v2,
                                         w3, g3, b3, m3, v3, w1s, w2s, w3s, sh1, sh2, sh3);
    passA<<<Bb * 640, 256, 0, stream>>>(feature, w1s, sh1, G1);
    passB<<<(Bb * TPB) / G, 256, 0, stream>>>(G1, feature, neigh, w2s, w3s,
                                              sh2, sh3, out);
}